// Round 5
// baseline (157.153 us; speedup 1.0000x reference)
//
#include <hip/hip_runtime.h>
#include <hip/hip_bf16.h>

#define BH    32
#define SEQ   2048
#define DK    64
#define QBLK  256
#define KBLK  64
#define NIT   (SEQ / KBLK)
#define KSTR  72   // LDS row stride in bf16 elems (144 B, 16B-aligned)

typedef short  short8  __attribute__((ext_vector_type(8)));
typedef float  f32x4   __attribute__((ext_vector_type(4)));
typedef float  float4v __attribute__((ext_vector_type(4)));
typedef unsigned short ushort4v __attribute__((ext_vector_type(4)));
typedef unsigned short ushort8v __attribute__((ext_vector_type(8)));

__device__ __forceinline__ unsigned short f2bf(float f) {
    unsigned int u = __builtin_bit_cast(unsigned int, f);
    u += 0x7FFFu + ((u >> 16) & 1u);   // RNE
    return (unsigned short)(u >> 16);
}

#if __has_builtin(__builtin_amdgcn_exp2f)
#define EXP2F(x) __builtin_amdgcn_exp2f(x)
#else
#define EXP2F(x) exp2f(x)
#endif

// ---------------- kernel 1: pack K (bf16) + V^T (bf16) into workspace ----------------
__global__ __launch_bounds__(256)
void pack_kv(const float* __restrict__ K, const float* __restrict__ V,
             unsigned short* __restrict__ Kbf, unsigned short* __restrict__ Vt)
{
    __shared__ unsigned short tl[DK][KSTR];
    const int b   = blockIdx.x;
    const int kb  = blockIdx.y * KBLK;
    const int tid = threadIdx.x;
    const int r   = tid >> 2;           // row 0..63
    const int c   = (tid & 3) * 16;     // col base

    // K: straight fp32 -> bf16, layout unchanged [ki][d]
    {
        const float* src = K + ((size_t)b * SEQ + kb + r) * DK + c;
        float4v a0 = *(const float4v*)(src);
        float4v a1 = *(const float4v*)(src + 4);
        float4v a2 = *(const float4v*)(src + 8);
        float4v a3 = *(const float4v*)(src + 12);
        ushort8v o0, o1;
        #pragma unroll
        for (int e = 0; e < 4; ++e) {
            o0[e] = f2bf(a0[e]); o0[e + 4] = f2bf(a1[e]);
            o1[e] = f2bf(a2[e]); o1[e + 4] = f2bf(a3[e]);
        }
        unsigned short* dst = Kbf + ((size_t)b * SEQ + kb + r) * DK + c;
        *(ushort8v*)(dst)     = o0;
        *(ushort8v*)(dst + 8) = o1;
    }
    // V: fp32 -> bf16 + transpose via LDS -> Vt[b][d][ki]
    {
        const float* src = V + ((size_t)b * SEQ + kb + r) * DK + c;
        float4v a0 = *(const float4v*)(src);
        float4v a1 = *(const float4v*)(src + 4);
        float4v a2 = *(const float4v*)(src + 8);
        float4v a3 = *(const float4v*)(src + 12);
        #pragma unroll
        for (int e = 0; e < 4; ++e) {
            tl[c + e     ][r] = f2bf(a0[e]);
            tl[c + e + 4 ][r] = f2bf(a1[e]);
            tl[c + e + 8 ][r] = f2bf(a2[e]);
            tl[c + e + 12][r] = f2bf(a3[e]);
        }
    }
    __syncthreads();
    {
        const int d  = tid >> 2;
        const int ch = (tid & 3) * 16;
        ushort8v w0 = *(const ushort8v*)(&tl[d][ch]);
        ushort8v w1 = *(const ushort8v*)(&tl[d][ch + 8]);
        unsigned short* dst = Vt + ((size_t)b * DK + d) * SEQ + kb + ch;
        *(ushort8v*)(dst)     = w0;
        *(ushort8v*)(dst + 8) = w1;
    }
}

// ---------------- kernel 2: attention from bf16 K / V^T ----------------
__global__ __launch_bounds__(1024, 4)
void sdpa_bf16(const float* __restrict__ Q, const unsigned short* __restrict__ Kbf,
               const unsigned short* __restrict__ Vt, const float* __restrict__ M,
               float* __restrict__ O)
{
    __shared__ unsigned short sK [KBLK][KSTR];     // K tile [ki][d]
    __shared__ unsigned short sVt[DK][KSTR];       // V^T tile [d][ki]
    __shared__ unsigned short sP [16][16][KSTR];   // per-wave P [q_local][ki]

    const int tid  = threadIdx.x;
    const int wave = tid >> 6;
    const int lane = tid & 63;
    const int g    = lane >> 4;
    const int li   = lane & 15;

    const int b  = blockIdx.x;
    const int qb = blockIdx.y * QBLK;

    // ---- Q fragment (A-operand), pre-scaled by (1/sqrt(DK)) * log2(e) ----
    const float QSC = 0.125f * 1.44269504f;
    short8 aq[2];
    {
        const size_t qoff = ((size_t)b * SEQ + (qb + wave * 16 + li)) * DK;
        #pragma unroll
        for (int kk = 0; kk < 2; ++kk) {
            const float* qp = Q + qoff + kk * 32 + g * 8;
            float4v q0 = *(const float4v*)(qp);
            float4v q1 = *(const float4v*)(qp + 4);
            #pragma unroll
            for (int i = 0; i < 4; ++i) {
                aq[kk][i]     = (short)f2bf(q0[i] * QSC);
                aq[kk][i + 4] = (short)f2bf(q1[i] * QSC);
            }
        }
    }

    // staging: 1024 threads x 8B = full 8KB tile each for K and V^T
    const int sr = tid >> 4;            // row (K: ki, V^T: d)
    const int sc = (tid & 15) * 4;      // 4 bf16 elems within row

    const unsigned short* kp = Kbf + (size_t)b * SEQ * DK + (size_t)sr * DK + sc;
    const unsigned short* vp = Vt  + (size_t)b * DK * SEQ + (size_t)sr * SEQ + sc;
    const float* mbase = M + ((size_t)b * SEQ + (qb + wave * 16 + g * 4)) * SEQ + li;

    // prologue: issue loads for tile 0
    ushort4v kreg = *(const ushort4v*)kp;
    ushort4v vreg = *(const ushort4v*)vp;

    f32x4 oacc[4] = {};
    float lsum[4] = {0.f, 0.f, 0.f, 0.f};

    for (int it = 0; it < NIT; ++it) {
        __syncthreads();   // previous compute's LDS reads done
        *(ushort4v*)(&sK [sr][sc]) = kreg;   // waits on in-flight loads
        *(ushort4v*)(&sVt[sr][sc]) = vreg;
        __syncthreads();

        // ---- mask loads for THIS tile ----
        float mk[4][4];
        {
            const float* mp = mbase + (size_t)it * KBLK;
            #pragma unroll
            for (int r = 0; r < 4; ++r)
                #pragma unroll
                for (int t = 0; t < 4; ++t)
                    mk[r][t] = mp[(size_t)r * SEQ + t * 16];
        }

        // ---- prefetch next K/V tile into regs ----
        if (it + 1 < NIT) {
            kp += KBLK * DK;   // next 64 ki rows
            vp += KBLK;        // next 64 ki cols within each d row
            kreg = *(const ushort4v*)kp;
            vreg = *(const ushort4v*)vp;
        }

        // ---- S = Q K^T ----
        f32x4 sacc[4] = {};
        #pragma unroll
        for (int t = 0; t < 4; ++t) {
            #pragma unroll
            for (int kk = 0; kk < 2; ++kk) {
                short8 bk = *(const short8*)(&sK[t * 16 + li][kk * 32 + g * 8]);
                sacc[t] = __builtin_amdgcn_mfma_f32_16x16x32_bf16(aq[kk], bk, sacc[t], 0, 0, 0);
            }
        }

        // ---- max-free softmax: p = exp2(s_scaled * mask) ----
        #pragma unroll
        for (int r = 0; r < 4; ++r) {
            float p0 = EXP2F(sacc[0][r] * mk[r][0]);
            float p1 = EXP2F(sacc[1][r] * mk[r][1]);
            float p2 = EXP2F(sacc[2][r] * mk[r][2]);
            float p3 = EXP2F(sacc[3][r] * mk[r][3]);
            lsum[r] += (p0 + p1) + (p2 + p3);
            sP[wave][g * 4 + r][0 * 16 + li] = f2bf(p0);
            sP[wave][g * 4 + r][1 * 16 + li] = f2bf(p1);
            sP[wave][g * 4 + r][2 * 16 + li] = f2bf(p2);
            sP[wave][g * 4 + r][3 * 16 + li] = f2bf(p3);
        }
        // sP is per-wave: wave-internal write->read, no barrier needed

        // ---- O += P V ----
        #pragma unroll
        for (int kk = 0; kk < 2; ++kk) {
            short8 pa = *(const short8*)(&sP[wave][li][kk * 32 + g * 8]);
            #pragma unroll
            for (int dt = 0; dt < 4; ++dt) {
                short8 bv = *(const short8*)(&sVt[dt * 16 + li][kk * 32 + g * 8]);
                oacc[dt] = __builtin_amdgcn_mfma_f32_16x16x32_bf16(pa, bv, oacc[dt], 0, 0, 0);
            }
        }
    }

    // ---- epilogue ----
    #pragma unroll
    for (int r = 0; r < 4; ++r) {
        float l = lsum[r];
        l += __shfl_xor(l, 1);
        l += __shfl_xor(l, 2);
        l += __shfl_xor(l, 4);
        l += __shfl_xor(l, 8);
        float inv = 1.0f / l;
        size_t orow = ((size_t)b * SEQ + (qb + wave * 16 + g * 4 + r)) * DK;
        #pragma unroll
        for (int dt = 0; dt < 4; ++dt)
            O[orow + dt * 16 + li] = oacc[dt][r] * inv;
    }
}

// ---------------- fallback: round-2 single-kernel (fp32 K/V) ----------------
__global__ __launch_bounds__(1024, 4)
void sdpa_f32(const float* __restrict__ Q, const float* __restrict__ K,
              const float* __restrict__ V, const float* __restrict__ M,
              float* __restrict__ O)
{
    __shared__ unsigned short sK [KBLK][KSTR];
    __shared__ unsigned short sVt[DK][KSTR];
    __shared__ unsigned short sP [16][16][KSTR];

    const int tid  = threadIdx.x;
    const int wave = tid >> 6;
    const int lane = tid & 63;
    const int g    = lane >> 4;
    const int li   = lane & 15;

    const int b  = blockIdx.x;
    const int qb = blockIdx.y * QBLK;

    const float* Kb = K + (size_t)b * SEQ * DK;
    const float* Vb = V + (size_t)b * SEQ * DK;

    const float QSC = 0.125f * 1.44269504f;
    short8 aq[2];
    {
        const size_t qoff = ((size_t)b * SEQ + (qb + wave * 16 + li)) * DK;
        #pragma unroll
        for (int kk = 0; kk < 2; ++kk) {
            const float* qp = Q + qoff + kk * 32 + g * 8;
            float4v q0 = *(const float4v*)(qp);
            float4v q1 = *(const float4v*)(qp + 4);
            #pragma unroll
            for (int i = 0; i < 4; ++i) {
                aq[kk][i]     = (short)f2bf(q0[i] * QSC);
                aq[kk][i + 4] = (short)f2bf(q1[i] * QSC);
            }
        }
    }

    const int sr = tid >> 4;
    const int sc = (tid & 15) * 4;
    const int vd = tid & 63;
    const int vk = (tid >> 6) * 4;

    const float* kp = Kb + (size_t)sr * DK + sc;
    const float* vp = Vb + (size_t)vk * DK + vd;
    const float* mbase = M + ((size_t)b * SEQ + (qb + wave * 16 + g * 4)) * SEQ + li;

    float4v kreg = *(const float4v*)kp;
    float vreg0 = vp[0 * DK], vreg1 = vp[1 * DK], vreg2 = vp[2 * DK], vreg3 = vp[3 * DK];

    f32x4 oacc[4] = {};
    float lsum[4] = {0.f, 0.f, 0.f, 0.f};

    for (int it = 0; it < NIT; ++it) {
        __syncthreads();
        {
            ushort4v pk;
            pk[0] = f2bf(kreg[0]); pk[1] = f2bf(kreg[1]);
            pk[2] = f2bf(kreg[2]); pk[3] = f2bf(kreg[3]);
            *(ushort4v*)(&sK[sr][sc]) = pk;
            ushort4v pv_;
            pv_[0] = f2bf(vreg0); pv_[1] = f2bf(vreg1);
            pv_[2] = f2bf(vreg2); pv_[3] = f2bf(vreg3);
            *(ushort4v*)(&sVt[vd][vk]) = pv_;
        }
        __syncthreads();

        float mk[4][4];
        {
            const float* mp = mbase + (size_t)it * KBLK;
            #pragma unroll
            for (int r = 0; r < 4; ++r)
                #pragma unroll
                for (int t = 0; t < 4; ++t)
                    mk[r][t] = mp[(size_t)r * SEQ + t * 16];
        }

        if (it + 1 < NIT) {
            kp += KBLK * DK;  vp += KBLK * DK;
            kreg = *(const float4v*)kp;
            vreg0 = vp[0 * DK]; vreg1 = vp[1 * DK];
            vreg2 = vp[2 * DK]; vreg3 = vp[3 * DK];
        }

        f32x4 sacc[4] = {};
        #pragma unroll
        for (int t = 0; t < 4; ++t) {
            #pragma unroll
            for (int kk = 0; kk < 2; ++kk) {
                short8 bk = *(const short8*)(&sK[t * 16 + li][kk * 32 + g * 8]);
                sacc[t] = __builtin_amdgcn_mfma_f32_16x16x32_bf16(aq[kk], bk, sacc[t], 0, 0, 0);
            }
        }

        #pragma unroll
        for (int r = 0; r < 4; ++r) {
            float p0 = EXP2F(sacc[0][r] * mk[r][0]);
            float p1 = EXP2F(sacc[1][r] * mk[r][1]);
            float p2 = EXP2F(sacc[2][r] * mk[r][2]);
            float p3 = EXP2F(sacc[3][r] * mk[r][3]);
            lsum[r] += (p0 + p1) + (p2 + p3);
            sP[wave][g * 4 + r][0 * 16 + li] = f2bf(p0);
            sP[wave][g * 4 + r][1 * 16 + li] = f2bf(p1);
            sP[wave][g * 4 + r][2 * 16 + li] = f2bf(p2);
            sP[wave][g * 4 + r][3 * 16 + li] = f2bf(p3);
        }

        #pragma unroll
        for (int kk = 0; kk < 2; ++kk) {
            short8 pa = *(const short8*)(&sP[wave][li][kk * 32 + g * 8]);
            #pragma unroll
            for (int dt = 0; dt < 4; ++dt) {
                short8 bv = *(const short8*)(&sVt[dt * 16 + li][kk * 32 + g * 8]);
                oacc[dt] = __builtin_amdgcn_mfma_f32_16x16x32_bf16(pa, bv, oacc[dt], 0, 0, 0);
            }
        }
    }

    #pragma unroll
    for (int r = 0; r < 4; ++r) {
        float l = lsum[r];
        l += __shfl_xor(l, 1);
        l += __shfl_xor(l, 2);
        l += __shfl_xor(l, 4);
        l += __shfl_xor(l, 8);
        float inv = 1.0f / l;
        size_t orow = ((size_t)b * SEQ + (qb + wave * 16 + g * 4 + r)) * DK;
        #pragma unroll
        for (int dt = 0; dt < 4; ++dt)
            O[orow + dt * 16 + li] = oacc[dt][r] * inv;
    }
}

extern "C" void kernel_launch(void* const* d_in, const int* in_sizes, int n_in,
                              void* d_out, int out_size, void* d_ws, size_t ws_size,
                              hipStream_t stream) {
    const float* q = (const float*)d_in[0];
    const float* k = (const float*)d_in[1];
    const float* v = (const float*)d_in[2];
    const float* m = (const float*)d_in[3];
    float* o = (float*)d_out;

    const size_t kv_elems = (size_t)BH * SEQ * DK;       // per array
    const size_t need     = kv_elems * 2 * sizeof(unsigned short);  // 16 MiB

    if (ws_size >= need) {
        unsigned short* Kbf = (unsigned short*)d_ws;
        unsigned short* Vt  = Kbf + kv_elems;
        pack_kv<<<dim3(BH, SEQ / KBLK), dim3(256), 0, stream>>>(k, v, Kbf, Vt);
        // grid.x = head: all q-blocks of a head on one XCD (linear id % 8).
        sdpa_bf16<<<dim3(BH, SEQ / QBLK), dim3(1024), 0, stream>>>(q, Kbf, Vt, m, o);
    } else {
        sdpa_f32<<<dim3(BH, SEQ / QBLK), dim3(1024), 0, stream>>>(q, k, v, m, o);
    }
}

// Round 6
// 137.972 us; speedup vs baseline: 1.1390x; 1.1390x over previous
//
#include <hip/hip_runtime.h>
#include <hip/hip_bf16.h>

#define BH    32
#define SEQ   2048
#define DK    64
#define QBLK  256
#define KBLK  64
#define NIT   (SEQ / KBLK)
#define KSTR  72   // LDS row stride in bf16 elems (144 B, 16B-aligned)

typedef short  short8  __attribute__((ext_vector_type(8)));
typedef float  f32x4   __attribute__((ext_vector_type(4)));
typedef float  float4v __attribute__((ext_vector_type(4)));
typedef unsigned short ushort4v __attribute__((ext_vector_type(4)));

__device__ __forceinline__ unsigned short f2bf(float f) {
    unsigned int u = __builtin_bit_cast(unsigned int, f);
    u += 0x7FFFu + ((u >> 16) & 1u);   // RNE
    return (unsigned short)(u >> 16);
}

#if __has_builtin(__builtin_amdgcn_exp2f)
#define EXP2F(x) __builtin_amdgcn_exp2f(x)
#else
#define EXP2F(x) exp2f(x)
#endif

__global__ __launch_bounds__(1024, 4)
void sdpa_kernel(const float* __restrict__ Q, const float* __restrict__ K,
                 const float* __restrict__ V, const float* __restrict__ M,
                 float* __restrict__ O)
{
    __shared__ unsigned short sK [2][KBLK][KSTR];   // K tile [buf][ki][d]
    __shared__ unsigned short sVt[2][DK][KSTR];     // V^T tile [buf][d][ki]
    __shared__ unsigned short sP [16][16][KSTR];    // per-wave P [q_local][ki]

    const int tid  = threadIdx.x;
    const int wave = tid >> 6;
    const int lane = tid & 63;
    const int g    = lane >> 4;
    const int li   = lane & 15;

    const int b  = blockIdx.x;                 // head; all q-blocks of a head on one XCD
    const int qb = blockIdx.y * QBLK;

    const float* Kb = K + (size_t)b * SEQ * DK;
    const float* Vb = V + (size_t)b * SEQ * DK;

    // ---- Q fragment (A-operand), pre-scaled by (1/sqrt(DK)) * log2(e) ----
    const float QSC = 0.125f * 1.44269504f;
    short8 aq[2];
    {
        const size_t qoff = ((size_t)b * SEQ + (qb + wave * 16 + li)) * DK;
        #pragma unroll
        for (int kk = 0; kk < 2; ++kk) {
            const float* qp = Q + qoff + kk * 32 + g * 8;
            float4v q0 = *(const float4v*)(qp);
            float4v q1 = *(const float4v*)(qp + 4);
            #pragma unroll
            for (int i = 0; i < 4; ++i) {
                aq[kk][i]     = (short)f2bf(q0[i] * QSC);
                aq[kk][i + 4] = (short)f2bf(q1[i] * QSC);
            }
        }
    }

    // staging assignments (1024 threads)
    const int sr = tid >> 4;            // K: row 0..63
    const int sc = (tid & 15) * 4;      // K: col base (4 floats)
    const int vd = tid & 63;            // V^T: d
    const int vk = (tid >> 6) * 4;      // V^T: ki base (4 rows)

    const float* kp = Kb + (size_t)sr * DK + sc;
    const float* vp = Vb + (size_t)vk * DK + vd;
    const float* mbase = M + ((size_t)b * SEQ + (qb + wave * 16 + g * 4)) * SEQ + li;

    // ---- prologue: tile 0 -> buf0; prefetch tile 1; prefetch mask 0 ----
    float4v kreg = *(const float4v*)kp;
    float vreg0 = vp[0 * DK], vreg1 = vp[1 * DK], vreg2 = vp[2 * DK], vreg3 = vp[3 * DK];
    {
        ushort4v pk;
        pk[0] = f2bf(kreg[0]); pk[1] = f2bf(kreg[1]);
        pk[2] = f2bf(kreg[2]); pk[3] = f2bf(kreg[3]);
        *(ushort4v*)(&sK[0][sr][sc]) = pk;
        ushort4v pv_;
        pv_[0] = f2bf(vreg0); pv_[1] = f2bf(vreg1);
        pv_[2] = f2bf(vreg2); pv_[3] = f2bf(vreg3);
        *(ushort4v*)(&sVt[0][vd][vk]) = pv_;
    }
    kp += KBLK * DK;  vp += KBLK * DK;
    kreg = *(const float4v*)kp;
    vreg0 = vp[0 * DK]; vreg1 = vp[1 * DK]; vreg2 = vp[2 * DK]; vreg3 = vp[3 * DK];

    float mkA[4][4], mkB[4][4];
    #pragma unroll
    for (int r = 0; r < 4; ++r) {
        #pragma unroll
        for (int t = 0; t < 4; ++t)
            mkA[r][t] = mbase[(size_t)r * SEQ + t * 16];
    }

    __syncthreads();   // buf0 visible

    f32x4 oacc[4] = {};
    float lsum[4] = {0.f, 0.f, 0.f, 0.f};

// One iteration. CUR is a compile-time buffer index; MKC = this tile's mask
// (in regs, loaded last iteration), MKN = next tile's mask (issued first here:
// FIFO order means the staging-write's vmcnt wait for K/V tile IT+1 — issued
// last iteration BEFORE these — leaves the MKN loads in flight).
#define SDPA_BODY(IT, CUR, MKC, MKN)                                          \
    {                                                                         \
        if ((IT) + 1 < NIT) {                                                 \
            const float* mp = mbase + (size_t)((IT) + 1) * KBLK;              \
            _Pragma("unroll")                                                 \
            for (int r = 0; r < 4; ++r) {                                     \
                _Pragma("unroll")                                             \
                for (int t = 0; t < 4; ++t)                                   \
                    MKN[r][t] = mp[(size_t)r * SEQ + t * 16];                 \
            }                                                                 \
            ushort4v pk;                                                      \
            pk[0] = f2bf(kreg[0]); pk[1] = f2bf(kreg[1]);                     \
            pk[2] = f2bf(kreg[2]); pk[3] = f2bf(kreg[3]);                     \
            *(ushort4v*)(&sK[(CUR) ^ 1][sr][sc]) = pk;                        \
            ushort4v pv_;                                                     \
            pv_[0] = f2bf(vreg0); pv_[1] = f2bf(vreg1);                       \
            pv_[2] = f2bf(vreg2); pv_[3] = f2bf(vreg3);                       \
            *(ushort4v*)(&sVt[(CUR) ^ 1][vd][vk]) = pv_;                      \
            if ((IT) + 2 < NIT) {                                             \
                kp += KBLK * DK;  vp += KBLK * DK;                            \
                kreg = *(const float4v*)kp;                                   \
                vreg0 = vp[0 * DK]; vreg1 = vp[1 * DK];                       \
                vreg2 = vp[2 * DK]; vreg3 = vp[3 * DK];                       \
            }                                                                 \
        }                                                                     \
        f32x4 sacc[4] = {};                                                   \
        _Pragma("unroll")                                                     \
        for (int t = 0; t < 4; ++t) {                                         \
            _Pragma("unroll")                                                 \
            for (int kk = 0; kk < 2; ++kk) {                                  \
                short8 bk = *(const short8*)(&sK[CUR][t * 16 + li][kk * 32 + g * 8]); \
                sacc[t] = __builtin_amdgcn_mfma_f32_16x16x32_bf16(aq[kk], bk, sacc[t], 0, 0, 0); \
            }                                                                 \
        }                                                                     \
        _Pragma("unroll")                                                     \
        for (int r = 0; r < 4; ++r) {                                         \
            float p0 = EXP2F(sacc[0][r] * MKC[r][0]);                         \
            float p1 = EXP2F(sacc[1][r] * MKC[r][1]);                         \
            float p2 = EXP2F(sacc[2][r] * MKC[r][2]);                         \
            float p3 = EXP2F(sacc[3][r] * MKC[r][3]);                         \
            lsum[r] += (p0 + p1) + (p2 + p3);                                 \
            sP[wave][g * 4 + r][0 * 16 + li] = f2bf(p0);                      \
            sP[wave][g * 4 + r][1 * 16 + li] = f2bf(p1);                      \
            sP[wave][g * 4 + r][2 * 16 + li] = f2bf(p2);                      \
            sP[wave][g * 4 + r][3 * 16 + li] = f2bf(p3);                      \
        }                                                                     \
        _Pragma("unroll")                                                     \
        for (int kk = 0; kk < 2; ++kk) {                                      \
            short8 pa = *(const short8*)(&sP[wave][li][kk * 32 + g * 8]);     \
            _Pragma("unroll")                                                 \
            for (int dt = 0; dt < 4; ++dt) {                                  \
                short8 bv = *(const short8*)(&sVt[CUR][dt * 16 + li][kk * 32 + g * 8]); \
                oacc[dt] = __builtin_amdgcn_mfma_f32_16x16x32_bf16(pa, bv, oacc[dt], 0, 0, 0); \
            }                                                                 \
        }                                                                     \
        __syncthreads();                                                      \
    }

    for (int it = 0; it < NIT; it += 2) {
        SDPA_BODY(it,     0, mkA, mkB)
        SDPA_BODY(it + 1, 1, mkB, mkA)
    }
#undef SDPA_BODY

    // ---- epilogue: reduce row sums across the 16-lane group, normalize, store ----
    #pragma unroll
    for (int r = 0; r < 4; ++r) {
        float l = lsum[r];
        l += __shfl_xor(l, 1);
        l += __shfl_xor(l, 2);
        l += __shfl_xor(l, 4);
        l += __shfl_xor(l, 8);
        float inv = 1.0f / l;
        size_t orow = ((size_t)b * SEQ + (qb + wave * 16 + g * 4 + r)) * DK;
        #pragma unroll
        for (int dt = 0; dt < 4; ++dt)
            O[orow + dt * 16 + li] = oacc[dt][r] * inv;
    }
}

extern "C" void kernel_launch(void* const* d_in, const int* in_sizes, int n_in,
                              void* d_out, int out_size, void* d_ws, size_t ws_size,
                              hipStream_t stream) {
    const float* q = (const float*)d_in[0];
    const float* k = (const float*)d_in[1];
    const float* v = (const float*)d_in[2];
    const float* m = (const float*)d_in[3];
    float* o = (float*)d_out;

    // grid.x = head: linear dispatch id % 8 == head % 8 -> all 8 q-blocks of a
    // head on one XCD; 4 heads x 1 MB fp32 K/V per XCD ~ L2-resident.
    dim3 grid(BH, SEQ / QBLK);
    sdpa_kernel<<<grid, dim3(1024), 0, stream>>>(q, k, v, m, o);
}